// Round 1
// 3160.273 us; speedup vs baseline: 1.0240x; 1.0240x over previous
//
#include <hip/hip_runtime.h>
#include <math.h>

#define DIM 768
#define NHEAD 12
#define DHEAD 64
#define FFDIM 3072

typedef _Float16 v8h __attribute__((ext_vector_type(8)));
typedef float v4f __attribute__((ext_vector_type(4)));

__device__ __forceinline__ float gelu_f(float x) {
    float x3 = x * x * x;
    return 0.5f * x * (1.0f + tanhf(0.7978845608028654f * (x + 0.044715f * x3)));
}

// async global->LDS, 16B per lane; lds base must be wave-uniform (HW adds lane*16)
__device__ __forceinline__ void gl_lds16(const _Float16* g, _Float16* l) {
    __builtin_amdgcn_global_load_lds(
        (const __attribute__((address_space(1))) unsigned int*)(g),
        (__attribute__((address_space(3))) unsigned int*)(l),
        16, 0, 0);
}

// ================= MFMA GEMM: per-block weight set ===============================
// rows < bnd: encN weights, nt=3 (A1B1+A1B2+A2B1); rows >= bnd: bert weights, nt=1.
struct GemmP {
    const _Float16* A1; const _Float16* A2;
    const _Float16* eB1[3]; const _Float16* eB2[3]; const _Float16* bB1[3];
    float* C[3];
    _Float16* G1; _Float16* G2;
    int bnd;
};

// nbg: column-tile group size for the reuse-aware block ordering (must divide gridDim.x).
// Work order: z outer -> col-group -> row -> col-in-group inner, then bijectively
// chunked across the 8 XCDs so each XCD keeps one z's B panel L2-resident.
__global__ __launch_bounds__(256) void gemm_mfma(GemmP p, int M, int N, int K,
                                                 int epi, float cdiv, float gscale, int nbg)
{
    __shared__ _Float16 sm[2][4][128 * 32];   // double-buffered: 64 KB
    const int tid = threadIdx.x;
    const int w = tid >> 6, lane = tid & 63;
    const int lm = lane & 15, kg = lane >> 4;

    // ---- reuse-aware bijective XCD remap (perf-only; any permutation is correct) ----
    const int nb = (int)gridDim.x, mb = (int)gridDim.y;
    const int nwg = nb * mb * (int)gridDim.z;
    int lid = (int)blockIdx.x + nb * ((int)blockIdx.y + mb * (int)blockIdx.z);
    int qd = nwg >> 3, rm = nwg & 7;
    int xcd = lid & 7, pos = lid >> 3;
    int wid = (xcd < rm ? xcd * (qd + 1) : rm * (qd + 1) + (xcd - rm) * qd) + pos;
    int gsz = (nbg > 0 && (nb % nbg) == 0) ? nbg : 1;
    int ngrp = nb / gsz;
    int bxi = wid % gsz; int tt = wid / gsz;
    int by = tt % mb; tt /= mb;
    int bxg = tt % ngrp;
    int z = tt / ngrp;
    const int row0 = by << 7, col0 = (bxg * gsz + bxi) << 7;

    const int wm = (w >> 1) << 6, wn = (w & 1) << 6;
    const int rl = (w << 4) + (lane >> 2);
    const int cofs = (lane & 3) << 3;
    int nt; const _Float16 *B1p, *B2p;
    if (row0 < p.bnd) { nt = 3; B1p = p.eB1[z]; B2p = p.eB2[z]; }
    else             { nt = 1; B1p = p.bB1[z]; B2p = p.bB1[z]; }
    const _Float16* A1 = p.A1 + (size_t)row0 * K;
    const _Float16* A2 = p.A2 + (size_t)row0 * K;
    const _Float16* B1 = B1p + (size_t)col0 * K;
    const _Float16* B2 = B2p + (size_t)col0 * K;
    const int ldsLo = w * 512, ldsHi = (w + 4) * 512;
    const size_t gbase = (size_t)rl * K + cofs;

    v4f acc[4][4];
#pragma unroll
    for (int i = 0; i < 4; i++)
#pragma unroll
        for (int j = 0; j < 4; j++) acc[i][j] = (v4f){0.f, 0.f, 0.f, 0.f};

    auto stage = [&](int d, int k0) {
        size_t glo = gbase + k0;
        size_t ghi = glo + (size_t)64 * K;
        gl_lds16(A1 + glo, sm[d][0] + ldsLo); gl_lds16(A1 + ghi, sm[d][0] + ldsHi);
        gl_lds16(B1 + glo, sm[d][2] + ldsLo); gl_lds16(B1 + ghi, sm[d][2] + ldsHi);
        if (nt == 3) {
            gl_lds16(A2 + glo, sm[d][1] + ldsLo); gl_lds16(A2 + ghi, sm[d][1] + ldsHi);
            gl_lds16(B2 + glo, sm[d][3] + ldsLo); gl_lds16(B2 + ghi, sm[d][3] + ldsHi);
        }
    };

    const int nk = K >> 5;
    stage(0, 0);
    __syncthreads();   // drain prologue stage (compiler emits vmcnt(0) before barrier)
    for (int i = 0; i < nk; i++) {
        int cur = i & 1;
        // issue next tile's loads first: they fly under this tile's ds_read+MFMA,
        // and are drained by the single barrier at the bottom of the iteration.
        if (i + 1 < nk) stage(cur ^ 1, (i + 1) << 5);
        const _Float16* sA1 = sm[cur][0]; const _Float16* sA2 = sm[cur][1];
        const _Float16* sB1 = sm[cur][2]; const _Float16* sB2 = sm[cur][3];
        v8h a1[4], b1f[4];
#pragma unroll
        for (int i2 = 0; i2 < 4; i2++) {
            a1[i2]  = *(const v8h*)(sA1 + (wm + (i2 << 4) + lm) * 32 + (kg << 3));
            b1f[i2] = *(const v8h*)(sB1 + (wn + (i2 << 4) + lm) * 32 + (kg << 3));
        }
        if (nt == 3) {
            v8h a2[4], b2f[4];
#pragma unroll
            for (int i2 = 0; i2 < 4; i2++) {
                a2[i2]  = *(const v8h*)(sA2 + (wm + (i2 << 4) + lm) * 32 + (kg << 3));
                b2f[i2] = *(const v8h*)(sB2 + (wn + (i2 << 4) + lm) * 32 + (kg << 3));
            }
#pragma unroll
            for (int i2 = 0; i2 < 4; i2++)
#pragma unroll
                for (int j = 0; j < 4; j++) {
                    acc[i2][j] = __builtin_amdgcn_mfma_f32_16x16x32_f16(a1[i2], b1f[j], acc[i2][j], 0, 0, 0);
                    acc[i2][j] = __builtin_amdgcn_mfma_f32_16x16x32_f16(a1[i2], b2f[j], acc[i2][j], 0, 0, 0);
                    acc[i2][j] = __builtin_amdgcn_mfma_f32_16x16x32_f16(a2[i2], b1f[j], acc[i2][j], 0, 0, 0);
                }
        } else {
#pragma unroll
            for (int i2 = 0; i2 < 4; i2++)
#pragma unroll
                for (int j = 0; j < 4; j++)
                    acc[i2][j] = __builtin_amdgcn_mfma_f32_16x16x32_f16(a1[i2], b1f[j], acc[i2][j], 0, 0, 0);
        }
        __syncthreads();
    }
    float* C = p.C[z];
#pragma unroll
    for (int i = 0; i < 4; i++) {
        int rb = row0 + wm + (i << 4) + (kg << 2);
#pragma unroll
        for (int j = 0; j < 4; j++) {
            int cc = col0 + wn + (j << 4) + lm;
#pragma unroll
            for (int r = 0; r < 4; r++) {
                float c = acc[i][j][r] * cdiv;
                size_t idx = (size_t)(rb + r) * N + cc;
                if (epi == 0) {
                    C[idx] = c;
                } else {
                    float gv = gelu_f(c) * gscale;
                    _Float16 g1 = (_Float16)gv;
                    p.G1[idx] = g1;
                    p.G2[idx] = (_Float16)(gv - (float)g1);
                }
            }
        }
    }
}

// ---------------- single-launch tiled weight transpose + split (x64) ----------------
struct WJobs {
    const float* src[12];
    _Float16* d1[12]; _Float16* d2[12];
    int K[12]; int N[12]; int start[12];
};
__global__ __launch_bounds__(256) void wsplit_tr(WJobs jb)
{
    __shared__ float sh[32 * 33];
    int bid = blockIdx.x;
    int ji = 0;
#pragma unroll
    for (int i = 1; i < 12; i++) if (bid >= jb.start[i]) ji = i;
    const float* src = jb.src[ji];
    _Float16* d1 = jb.d1[ji]; _Float16* d2 = jb.d2[ji];
    int K = jb.K[ji], N = jb.N[ji];
    int t = bid - jb.start[ji];
    int tilesN = N >> 5;
    int tk = t / tilesN, tn = t - tk * tilesN;
    int k0 = tk << 5, n0 = tn << 5;
    int c = threadIdx.x & 31, rr = threadIdx.x >> 5;
#pragma unroll
    for (int pph = 0; pph < 4; pph++) {
        int r = rr + (pph << 3);
        sh[c * 33 + r] = src[(size_t)(k0 + r) * N + n0 + c];
    }
    __syncthreads();
#pragma unroll
    for (int pph = 0; pph < 4; pph++) {
        int rn = rr + (pph << 3);
        float v = sh[rn * 33 + c] * 64.f;
        _Float16 b1 = (_Float16)v;
        size_t idx = (size_t)(n0 + rn) * K + k0 + c;
        d1[idx] = b1;
        if (d2) d2[idx] = (_Float16)(v - (float)b1);
    }
}

// ---------------- prefix build + pooled attention mask (his + cdd batched) ----------
__global__ __launch_bounds__(256) void build_prefix2(const int* __restrict__ hisSub,
    const float* __restrict__ hisMask, const float* __restrict__ hisAmask,
    const int* __restrict__ cddSub, const float* __restrict__ cddMask,
    const float* __restrict__ cddAmask,
    float* __restrict__ P, float* __restrict__ hisA, float* __restrict__ cddA)
{
    __shared__ float pref[64 * 64];
    int g = blockIdx.x;
    const int* sub; const float* mask; const float* amask; float* aout; int li;
    if (g < 400) { sub = hisSub; mask = hisMask; amask = hisAmask; aout = hisA; li = g; }
    else         { sub = cddSub; mask = cddMask; amask = cddAmask; aout = cddA; li = g - 400; }
    int tid = threadIdx.x;
    for (int t = tid; t < 4096; t += 256) pref[t] = 0.f;
    __syncthreads();
    if (tid < 64) {
        int r = sub[((size_t)li * 64 + tid) * 2 + 0];
        int c = sub[((size_t)li * 64 + tid) * 2 + 1];
        pref[(r << 6) + c] = 1.0f;
    }
    __syncthreads();
    float m = mask[li];
    int lane = tid & 63, w = tid >> 6;
    for (int s = (w << 4); s < (w << 4) + 16; s++) {
        float v = pref[(s << 6) + lane] * m;
        float rs = v;
#pragma unroll
        for (int o = 32; o; o >>= 1) rs += __shfl_down(rs, o);
        rs = __shfl(rs, 0);
        float nv = v / fmaxf(rs, 1e-12f);
        P[(((size_t)g << 6) + s) * 64 + lane] = nv;
        float av = nv * amask[((size_t)li << 6) + lane];
#pragma unroll
        for (int o = 32; o; o >>= 1) av += __shfl_down(av, o);
        if (lane == 0) aout[((size_t)li << 6) + s] = av;
    }
}

// ---------------- subword->token pooling, 16 rows/block, fused x64 split ------------
__global__ __launch_bounds__(256) void emb_pool2(const float* __restrict__ P,
    const int* __restrict__ encHis, const int* __restrict__ encCdd,
    const float* __restrict__ emb, float* __restrict__ X,
    _Float16* __restrict__ s1, _Float16* __restrict__ s2, int gOffHis, int gMid)
{
    int gl = blockIdx.x >> 2, q = blockIdx.x & 3;
    int g; const int* enc;
    if (gl < gMid) { g = gOffHis + gl; enc = encHis + (size_t)g * 64; }
    else { int gc = gl - gMid; g = 400 + gc; enc = encCdd + (size_t)gc * 64; }
    int tid = threadIdx.x;
    __shared__ float pw[16][64];
    __shared__ int tk[64];
    if (tid < 64) tk[tid] = enc[tid];
    for (int u = tid; u < 1024; u += 256) {
        int si = u >> 6, t = u & 63;
        pw[si][t] = P[((size_t)g * 64 + q * 16 + si) * 64 + t];
    }
    __syncthreads();
    float acc[16][3];
#pragma unroll
    for (int si = 0; si < 16; si++) { acc[si][0] = 0.f; acc[si][1] = 0.f; acc[si][2] = 0.f; }
    for (int t = 0; t < 64; t++) {
        const float* er = emb + (size_t)tk[t] * DIM;
        float e0 = er[tid], e1 = er[tid + 256], e2 = er[tid + 512];
#pragma unroll
        for (int si = 0; si < 16; si++) {
            float w = pw[si][t];
            acc[si][0] = fmaf(w, e0, acc[si][0]);
            acc[si][1] = fmaf(w, e1, acc[si][1]);
            acc[si][2] = fmaf(w, e2, acc[si][2]);
        }
    }
#pragma unroll
    for (int si = 0; si < 16; si++) {
        size_t base = ((size_t)gl * 64 + q * 16 + si) * DIM;
#pragma unroll
        for (int cci = 0; cci < 3; cci++) {
            int cc = tid + (cci << 8);
            float v = acc[si][cci];
            X[base + cc] = v;
            float xs = v * 64.f;
            _Float16 a = (_Float16)xs;
            s1[base + cc] = a;
            s2[base + cc] = (_Float16)(xs - (float)a);
        }
    }
}

// ---------------- fused S=64 attention (fp32 exact-class), batched masks ------------
__global__ __launch_bounds__(256) void attn_fused64(const float* __restrict__ Q,
    const float* __restrict__ Km, const float* __restrict__ V,
    const float* __restrict__ maskHis, const float* __restrict__ maskCdd, int gMid,
    _Float16* __restrict__ o1, _Float16* __restrict__ o2)
{
    __shared__ float Ks[64 * 65];
    __shared__ float Vs[64 * 65];
    __shared__ float Qs[64 * 65];
    int h = blockIdx.x % NHEAD;
    int g = blockIdx.x / NHEAD;
    const float* mrow = (g < gMid) ? maskHis + (size_t)g * 64
                                   : maskCdd + (size_t)(g - gMid) * 64;
    int tid = threadIdx.x, lane = tid & 63, w = tid >> 6;
    {
        int r = tid >> 2, c0 = (tid & 3) << 4;
        const float* qp = Q  + ((size_t)g * 64 + r) * DIM + h * DHEAD + c0;
        const float* kp = Km + ((size_t)g * 64 + r) * DIM + h * DHEAD + c0;
        const float* vp = V  + ((size_t)g * 64 + r) * DIM + h * DHEAD + c0;
#pragma unroll
        for (int u = 0; u < 16; u += 4) {
            float4 qv = *(const float4*)(qp + u);
            float4 kv = *(const float4*)(kp + u);
            float4 vv = *(const float4*)(vp + u);
            int o = r * 65 + c0 + u;
            Qs[o+0]=qv.x; Qs[o+1]=qv.y; Qs[o+2]=qv.z; Qs[o+3]=qv.w;
            Ks[o+0]=kv.x; Ks[o+1]=kv.y; Ks[o+2]=kv.z; Ks[o+3]=kv.w;
            Vs[o+0]=vv.x; Vs[o+1]=vv.y; Vs[o+2]=vv.z; Vs[o+3]=vv.w;
        }
    }
    __syncthreads();
    float mk = mrow[lane] > 0.f ? 0.f : -1e9f;
    for (int il = 0; il < 16; il++) {
        int i = (w << 4) + il;
        float d = 0.f;
        for (int t = 0; t < 64; t++) d = fmaf(Qs[i * 65 + t], Ks[lane * 65 + t], d);
        float l = d * 0.125f + mk;
        float mx = l;
#pragma unroll
        for (int o = 32; o; o >>= 1) mx = fmaxf(mx, __shfl_xor(mx, o));
        float e = expf(l - mx);
        float s = e;
#pragma unroll
        for (int o = 32; o; o >>= 1) s += __shfl_xor(s, o);
        float p = e / s;
        float acc = 0.f;
        for (int j = 0; j < 64; j++) {
            float pj = __shfl(p, j);
            acc = fmaf(pj, Vs[j * 65 + lane], acc);
        }
        size_t ob = ((size_t)g * 64 + i) * DIM + h * DHEAD + lane;
        float os = acc * 64.f;
        _Float16 h1 = (_Float16)os;
        o1[ob] = h1;
        o2[ob] = (_Float16)(os - (float)h1);
    }
}

// ---------------- MFMA flash attention S=400 (user BERT) ----------------
#define SSTR 449
__global__ __launch_bounds__(256) void attn_flash400(const float* __restrict__ Q,
    const float* __restrict__ Km, const float* __restrict__ V,
    const float* __restrict__ mask, _Float16* __restrict__ o1, _Float16* __restrict__ o2)
{
    __shared__ _Float16 Kt[64 * 64];
    __shared__ float Sc[16 * SSTR];
    int qt = blockIdx.x % 25;
    int h  = (blockIdx.x / 25) % NHEAD;
    int g  = blockIdx.x / (25 * NHEAD);
    int tid = threadIdx.x, w = tid >> 6, lane = tid & 63, lm = lane & 15, kg = lane >> 4;

    v8h aq0, aq1;
    {
        const float* qp = Q + ((size_t)(g * 400 + qt * 16 + lm)) * DIM + h * DHEAD;
#pragma unroll
        for (int u = 0; u < 8; u++) {
            aq0[u] = (_Float16)qp[kg * 8 + u];
            aq1[u] = (_Float16)qp[32 + kg * 8 + u];
        }
    }
    for (int jt = 0; jt < 7; jt++) {
        int j0 = jt * 64;
        __syncthreads();
        {
            int jr = tid >> 2, c0 = (tid & 3) << 4;
            int j = j0 + jr;
            _Float16* kd = Kt + jr * 64 + c0;
            if (j < 400) {
                const float* kp = Km + ((size_t)(g * 400 + j)) * DIM + h * DHEAD + c0;
#pragma unroll
                for (int u = 0; u < 16; u++) kd[u] = (_Float16)kp[u];
            } else {
#pragma unroll
                for (int u = 0; u < 16; u++) kd[u] = (_Float16)0.f;
            }
        }
        __syncthreads();
        v8h b0, b1;
#pragma unroll
        for (int u = 0; u < 8; u++) {
            b0[u] = Kt[(w * 16 + lm) * 64 + kg * 8 + u];
            b1[u] = Kt[(w * 16 + lm) * 64 + 32 + kg * 8 + u];
        }
        v4f c = {0.f, 0.f, 0.f, 0.f};
        c = __builtin_amdgcn_mfma_f32_16x16x32_f16(aq0, b0, c, 0, 0, 0);
        c = __builtin_amdgcn_mfma_f32_16x16x32_f16(aq1, b1, c, 0, 0, 0);
        int jj = j0 + w * 16 + lm;
        float mv = (jj < 400) ? (mask[g * 400 + jj] > 0.f ? 0.f : -1e9f) : -1e9f;
#pragma unroll
        for (int r = 0; r < 4; r++)
            Sc[(kg * 4 + r) * SSTR + jj] = c[r] * 0.125f + mv;
    }
    __syncthreads();
    for (int rr = 0; rr < 4; rr++) {
        int r = w * 4 + rr;
        float mx = -INFINITY;
#pragma unroll
        for (int c7 = 0; c7 < 7; c7++) mx = fmaxf(mx, Sc[r * SSTR + c7 * 64 + lane]);
#pragma unroll
        for (int o = 32; o; o >>= 1) mx = fmaxf(mx, __shfl_xor(mx, o));
        float s = 0.f;
        float ev[7];
#pragma unroll
        for (int c7 = 0; c7 < 7; c7++) { ev[c7] = expf(Sc[r * SSTR + c7 * 64 + lane] - mx); s += ev[c7]; }
#pragma unroll
        for (int o = 32; o; o >>= 1) s += __shfl_xor(s, o);
        float inv = 1.f / s;
#pragma unroll
        for (int c7 = 0; c7 < 7; c7++) Sc[r * SSTR + c7 * 64 + lane] = ev[c7] * inv;
    }
    __syncthreads();
    v4f o = {0.f, 0.f, 0.f, 0.f};
    for (int kc = 0; kc < 14; kc++) {
        v8h a, b;
#pragma unroll
        for (int u = 0; u < 8; u++) a[u] = (_Float16)Sc[lm * SSTR + kc * 32 + kg * 8 + u];
#pragma unroll
        for (int u = 0; u < 8; u++) {
            int j = kc * 32 + kg * 8 + u;
            b[u] = (j < 400) ? (_Float16)V[((size_t)(g * 400 + j)) * DIM + h * DHEAD + w * 16 + lm]
                             : (_Float16)0.f;
        }
        o = __builtin_amdgcn_mfma_f32_16x16x32_f16(a, b, o, 0, 0, 0);
    }
#pragma unroll
    for (int r = 0; r < 4; r++) {
        int qr = qt * 16 + kg * 4 + r;
        size_t ob = ((size_t)(g * 400 + qr)) * DIM + h * DHEAD + w * 16 + lm;
        float os = o[r] * 64.f;
        _Float16 h1 = (_Float16)os;
        o1[ob] = h1; o2[ob] = (_Float16)(os - (float)h1);
    }
}

// ---------------- LayerNorm(X + Y) with fused split / dual-out / cls ----------------
__global__ __launch_bounds__(256) void add_ln2(const float* __restrict__ X,
    const float* __restrict__ Y, float* __restrict__ outA, float* __restrict__ outB,
    int bndRow, _Float16* __restrict__ S1, _Float16* __restrict__ S2, float ss,
    float* __restrict__ cls, int clsOffA, int clsOffB, int S)
{
    int r = blockIdx.x, tid = threadIdx.x;
    size_t base = (size_t)r * DIM;
    float v0 = X[base + tid] + Y[base + tid];
    float v1 = X[base + tid + 256] + Y[base + tid + 256];
    float v2 = X[base + tid + 512] + Y[base + tid + 512];
    __shared__ float red[256];
    red[tid] = v0 + v1 + v2; __syncthreads();
    for (int o = 128; o; o >>= 1) { if (tid < o) red[tid] += red[tid + o]; __syncthreads(); }
    float mu = red[0] * (1.f / 768.f);
    __syncthreads();
    float d0 = v0 - mu, d1 = v1 - mu, d2 = v2 - mu;
    red[tid] = d0 * d0 + d1 * d1 + d2 * d2; __syncthreads();
    for (int o = 128; o; o >>= 1) { if (tid < o) red[tid] += red[tid + o]; __syncthreads(); }
    float rstd = rsqrtf(red[0] * (1.f / 768.f) + 1e-12f);
    float o0 = d0 * rstd, o1 = d1 * rstd, o2 = d2 * rstd;
    float* Out = (r < bndRow) ? outA + base : outB + (size_t)(r - bndRow) * DIM;
    Out[tid] = o0; Out[tid + 256] = o1; Out[tid + 512] = o2;
    if (S1) {
        float x0 = o0 * ss, x1 = o1 * ss, x2 = o2 * ss;
        _Float16 a0 = (_Float16)x0, a1 = (_Float16)x1, a2 = (_Float16)x2;
        S1[base + tid] = a0;        S2[base + tid] = (_Float16)(x0 - (float)a0);
        S1[base + tid + 256] = a1;  S2[base + tid + 256] = (_Float16)(x1 - (float)a1);
        S1[base + tid + 512] = a2;  S2[base + tid + 512] = (_Float16)(x2 - (float)a2);
    }
    if (cls && (r % S) == 0) {
        int g = (r < bndRow) ? clsOffA + r / S : clsOffB + (r - bndRow) / S;
        float* cd = cls + (size_t)g * DIM;
        cd[tid] = o0; cd[tid + 256] = o1; cd[tid + 512] = o2;
    }
}

// ---------------- legacy fp32 SIMT GEMM (tiny proj GEMMs only) ----------------
__global__ __launch_bounds__(256) void gemm_kernel(const float* __restrict__ A,
    const float* __restrict__ B, float* __restrict__ C,
    int M, int N, int Kd, int epi, const float* __restrict__ bias)
{
    __shared__ float As[16][64];
    __shared__ float Bs[16][64];
    int tid = threadIdx.x;
    int tx = tid & 15, ty = tid >> 4;
    int row0 = blockIdx.y << 6, col0 = blockIdx.x << 6;
    int ar = tid >> 2, ak = (tid & 3) << 2;
    int bc = tid & 63, bk0 = tid >> 6;
    const float* Ap = A + (size_t)(row0 + ar) * Kd + ak;
    const float* Bp = B + (size_t)bk0 * N + col0 + bc;
    bool aval = (row0 + ar) < M;
    float acc[4][4];
#pragma unroll
    for (int i = 0; i < 4; i++)
#pragma unroll
        for (int j = 0; j < 4; j++) acc[i][j] = 0.f;
    for (int k0 = 0; k0 < Kd; k0 += 16) {
        float4 a4 = make_float4(0.f, 0.f, 0.f, 0.f);
        if (aval) a4 = *(const float4*)(Ap + k0);
        As[ak + 0][ar] = a4.x; As[ak + 1][ar] = a4.y;
        As[ak + 2][ar] = a4.z; As[ak + 3][ar] = a4.w;
#pragma unroll
        for (int i = 0; i < 4; i++)
            Bs[bk0 + 4 * i][bc] = Bp[(size_t)(k0 + 4 * i) * N];
        __syncthreads();
#pragma unroll
        for (int kk = 0; kk < 16; kk++) {
            float4 av = *(const float4*)&As[kk][ty << 2];
            float4 bv = *(const float4*)&Bs[kk][tx << 2];
            float aa[4] = {av.x, av.y, av.z, av.w};
            float bb[4] = {bv.x, bv.y, bv.z, bv.w};
#pragma unroll
            for (int i = 0; i < 4; i++)
#pragma unroll
                for (int j = 0; j < 4; j++)
                    acc[i][j] = fmaf(aa[i], bb[j], acc[i][j]);
        }
        __syncthreads();
    }
#pragma unroll
    for (int i = 0; i < 4; i++) {
        int r = row0 + (ty << 2) + i;
        if (r >= M) continue;
        float v[4];
#pragma unroll
        for (int j = 0; j < 4; j++) {
            float x = acc[i][j];
            if (epi == 1) x = gelu_f(x);
            else if (epi == 2) x = tanhf(x + bias[col0 + (tx << 2) + j]);
            v[j] = x;
        }
        *(float4*)(C + (size_t)r * N + col0 + (tx << 2)) = make_float4(v[0], v[1], v[2], v[3]);
    }
}

// ---------------- user attention pooling (kept: exact order, feeds kid) -------------
__global__ __launch_bounds__(256) void user_pool_kernel(const float* __restrict__ cls,
    const float* __restrict__ qU, float* __restrict__ user0)
{
    int b = blockIdx.x, tid = threadIdx.x;
    __shared__ float red[256];
    __shared__ float wv[64];
    const float scale = 0.03608439182435161f;
    for (int n = 0; n < 50; n++) {
        const float* cr = cls + ((size_t)(b * 50 + n)) * DIM;
        float d = 0.f;
        for (int t = tid; t < DIM; t += 256) d = fmaf(cr[t], qU[t], d);
        red[tid] = d; __syncthreads();
        for (int o = 128; o; o >>= 1) { if (tid < o) red[tid] += red[tid + o]; __syncthreads(); }
        if (tid == 0) wv[n] = red[0] * scale;
        __syncthreads();
    }
    if (tid == 0) {
        float mx = -INFINITY;
        for (int n = 0; n < 50; n++) mx = fmaxf(mx, wv[n]);
        float s = 0.f;
        for (int n = 0; n < 50; n++) { float e = expf(wv[n] - mx); wv[n] = e; s += e; }
        float inv = 1.f / s;
        for (int n = 0; n < 50; n++) wv[n] *= inv;
    }
    __syncthreads();
    for (int d = tid; d < DIM; d += 256) {
        float a = 0.f;
        for (int n = 0; n < 50; n++) a = fmaf(wv[n], cls[((size_t)(b * 50 + n)) * DIM + d], a);
        user0[(size_t)b * DIM + d] = a;
    }
}

// ---------------- personalized-term scores + stable top-8 ----------------
__global__ __launch_bounds__(256) void topk_kernel(const float* __restrict__ hid,
    const float* __restrict__ user0, const float* __restrict__ attn,
    float* __restrict__ kid_f, int* __restrict__ kid_i, float* __restrict__ ps_mask)
{
    int bn = blockIdx.x;
    int b = bn / 50;
    int tid = threadIdx.x, lane = tid & 63, w = tid >> 6;
    __shared__ float sc[64];
    const float* u = user0 + (size_t)b * DIM;
    const float scale = 0.03608439182435161f;
    for (int s = w; s < 64; s += 4) {
        const float* hr = hid + ((size_t)bn * 64 + s) * DIM;
        float d = 0.f;
        for (int t = lane; t < DIM; t += 64) d = fmaf(hr[t], u[t], d);
#pragma unroll
        for (int o = 32; o; o >>= 1) d += __shfl_down(d, o);
        if (lane == 0) {
            float a = attn[(size_t)bn * 64 + s];
            sc[s] = (a > 0.f) ? d * scale : -1e9f;
        }
    }
    __syncthreads();
    if (tid == 0) {
        unsigned long long used = 0ull;
        for (int k = 0; k < 8; k++) {
            float best = -INFINITY; int bi = 0;
            for (int s = 0; s < 64; s++) {
                if ((used >> s) & 1ull) continue;
                if (sc[s] > best) { best = sc[s]; bi = s; }
            }
            used |= (1ull << bi);
            kid_i[bn * 8 + k] = bi;
            kid_f[bn * 8 + k] = (float)bi;
            ps_mask[bn * 8 + k] = attn[(size_t)bn * 64 + bi];
        }
    }
}

// ---------------- gather with fused x64 split ----------------
__global__ void gather2(const float* __restrict__ hid, const int* __restrict__ kid_i,
    float* __restrict__ X, _Float16* __restrict__ s1, _Float16* __restrict__ s2)
{
    int r = blockIdx.x, tid = threadIdx.x;
    int s = kid_i[r];
    int bn = r >> 3;
    const float* src = hid + ((size_t)bn * 64 + s) * DIM;
    size_t base = (size_t)r * DIM;
#pragma unroll
    for (int cci = 0; cci < 3; cci++) {
        int cc = tid + (cci << 8);
        float v = src[cc];
        X[base + cc] = v;
        float xs = v * 64.f;
        _Float16 a = (_Float16)xs;
        s1[base + cc] = a;
        s2[base + cc] = (_Float16)(xs - (float)a);
    }
}

__global__ __launch_bounds__(256) void final_kernel(const float* __restrict__ cdd_repr,
    const float* __restrict__ user_repr, float* __restrict__ out)
{
    int b = blockIdx.x, tid = threadIdx.x;
    __shared__ float red[256];
    __shared__ float sc[5];
    const float scale = 0.03608439182435161f;
    for (int c = 0; c < 5; c++) {
        const float* cr = cdd_repr + ((size_t)(b * 5 + c)) * DIM;
        const float* ur = user_repr + (size_t)b * DIM;
        float d = 0.f;
        for (int t = tid; t < DIM; t += 256) d = fmaf(cr[t], ur[t], d);
        red[tid] = d; __syncthreads();
        for (int o = 128; o; o >>= 1) { if (tid < o) red[tid] += red[tid + o]; __syncthreads(); }
        if (tid == 0) sc[c] = red[0] * scale;
        __syncthreads();
    }
    if (tid == 0) {
        float mx = -INFINITY;
        for (int c = 0; c < 5; c++) mx = fmaxf(mx, sc[c]);
        float s = 0.f;
        for (int c = 0; c < 5; c++) s += expf(sc[c] - mx);
        float lse = logf(s) + mx;
        for (int c = 0; c < 5; c++) out[b * 5 + c] = sc[c] - lse;
    }
}

extern "C" void kernel_launch(void* const* d_in, const int* in_sizes, int n_in,
                              void* d_out, int out_size, void* d_ws, size_t ws_size,
                              hipStream_t stream)
{
    (void)in_sizes; (void)n_in; (void)out_size;
    const int*   cdd_sub   = (const int*)d_in[0];
    const int*   his_sub   = (const int*)d_in[1];
    const int*   cdd_enc   = (const int*)d_in[2];
    const int*   his_enc   = (const int*)d_in[3];
    const float* cdd_mask  = (const float*)d_in[4];
    const float* his_mask  = (const float*)d_in[5];
    const float* cdd_amask = (const float*)d_in[6];
    const float* his_amask = (const float*)d_in[7];
    const float* emb = (const float*)d_in[8];
    const float* bWsrc[6] = {(const float*)d_in[9],  (const float*)d_in[10], (const float*)d_in[11],
                             (const float*)d_in[12], (const float*)d_in[13], (const float*)d_in[14]};
    const float* eWsrc[6] = {(const float*)d_in[15], (const float*)d_in[16], (const float*)d_in[17],
                             (const float*)d_in[18], (const float*)d_in[19], (const float*)d_in[20]};
    const float* qU = (const float*)d_in[21];
    const float* pW = (const float*)d_in[22];
    const float* pb = (const float*)d_in[23];
    float* out = (float*)d_out;

    // ---- workspace-fitted chunk schedule (ws_size is process-constant: graph-safe) ----
    auto al256 = [](size_t b) { return (b + 255) & ~(size_t)255; };
    auto needBytes = [&](size_t RCx) -> size_t {
        size_t t = 0;
        t += 4 * al256(RCx * 768 * 4);          // R_X, R_Q, R_K, R_V
        t += 2 * al256(RCx * 768 * 2);          // s1h, s2h
        t += al256(RCx * 3072 * 2);             // g2h (also cdd-discard scratch)
        t += al256((size_t)440 * 4096 * 4);     // Pa
        t += al256((size_t)400 * 64 * 768 * 4); // hisH
        t += al256((size_t)448 * 768 * 4);      // cls
        t += 8 * al256(131072);                  // small buffers (overestimate)
        t += 3 * (4 * al256((size_t)589824 * 2) + 2 * al256((size_t)2359296 * 2)); // weights
        return t;
    };
    // NS = history seqs per chunk (even -> all row counts multiple of 128).
    // Chunk 0 additionally carries the 40 cdd seqs (2560 rows, bert weights).
    const int NSopts[9] = {400, 200, 134, 100, 66, 50, 34, 24, 10};
    int NS = 10;
    for (int i = 0; i < 9; i++) {
        size_t RCt = (size_t)NSopts[i] * 64 + 2560;
        if (needBytes(RCt) <= ws_size) { NS = NSopts[i]; break; }
    }
    const size_t RC = (size_t)NS * 64 + 2560;

    // ---- workspace carve (order must match needBytes) ----
    char* wsb = (char*)d_ws;
    size_t off = 0;
    auto allocB = [&](size_t bytes) { char* p = wsb + off; off += al256(bytes); return p; };
    float* R_X = (float*)allocB(RC * 768 * 4);
    float* R_Q = (float*)allocB(RC * 768 * 4);
    float* R_K = (float*)allocB(RC * 768 * 4);   // g1h aliases K+V during FFN
    float* R_V = (float*)allocB(RC * 768 * 4);
    _Float16* s1h = (_Float16*)allocB(RC * 768 * 2);
    _Float16* s2h = (_Float16*)allocB(RC * 768 * 2);
    _Float16* g2h = (_Float16*)allocB(RC * 3072 * 2);
    float* Pa   = (float*)allocB((size_t)440 * 4096 * 4);
    float* hisH = (float*)allocB((size_t)400 * 64 * 768 * 4);
    float* cls  = (float*)allocB((size_t)448 * 768 * 4);   // g 0..399 his, 400..439 cdd
    float* userC = (float*)allocB(131072);
    float* hisA  = (float*)allocB(131072);
    float* cddA  = (float*)allocB(131072);
    float* cddR  = (float*)allocB(131072);
    float* userR = (float*)allocB(131072);
    float* user0 = (float*)allocB(131072);
    float* psM   = (float*)allocB(131072);
    int*   kidI  = (int*)allocB(131072);
    size_t wsz[6] = {589824, 589824, 589824, 589824, 2359296, 2359296};
    _Float16 *eB1s[6], *eB2s[6], *bB1s[6];
    for (int i = 0; i < 6; i++) eB1s[i] = (_Float16*)allocB(wsz[i] * 2);
    for (int i = 0; i < 6; i++) eB2s[i] = (_Float16*)allocB(wsz[i] * 2);
    for (int i = 0; i < 6; i++) bB1s[i] = (_Float16*)allocB(wsz[i] * 2);
    _Float16* g1h = (_Float16*)R_K;       // M*3072 halves over R_K+R_V (M <= RC)
    float* cddTrash = (float*)g2h;        // cdd hidden-state sink (never read; g2h dead then)

    // ---- single-launch coalesced weight transpose+split (x64) ----
    int wk[6] = {768, 768, 768, 768, 768, 3072};
    int wn[6] = {768, 768, 768, 768, 3072, 768};
    {
        WJobs jb{};
        int st = 0;
        for (int i = 0; i < 6; i++) {
            jb.src[i] = eWsrc[i]; jb.d1[i] = eB1s[i]; jb.d2[i] = eB2s[i];
            jb.K[i] = wk[i]; jb.N[i] = wn[i]; jb.start[i] = st;
            st += (wk[i] >> 5) * (wn[i] >> 5);
        }
        for (int i = 0; i < 6; i++) {
            jb.src[6 + i] = bWsrc[i]; jb.d1[6 + i] = bB1s[i]; jb.d2[6 + i] = nullptr;
            jb.K[6 + i] = wk[i]; jb.N[6 + i] = wn[i]; jb.start[6 + i] = st;
            st += (wk[i] >> 5) * (wn[i] >> 5);
        }
        wsplit_tr<<<st, 256, 0, stream>>>(jb);
    }

    // ---- prefix matrices + pooled attn masks for all 440 sequences ----
    build_prefix2<<<440, 256, 0, stream>>>(his_sub, his_mask, his_amask,
                                           cdd_sub, cdd_mask, cdd_amask, Pa, hisA, cddA);

    auto mkP = [&](int sl, int bnd) {
        GemmP g{};
        g.A1 = s1h; g.A2 = s2h;
        for (int z = 0; z < 3; z++) {
            g.eB1[z] = eB1s[sl]; g.eB2[z] = eB2s[sl]; g.bB1[z] = bB1s[sl];
        }
        g.bnd = bnd;
        return g;
    };

    // ---- one transformer pass (rows<bnd: encN nt=3; rows>=bnd: bert nt=1) ----
    auto tf = [&](int M, int bnd, int nseqTot, int gMid, const float* mHis,
                  float* outA, float* outB, float* clsArena, int clsOffA, int clsOffB,
                  int S, bool userAttn) {
        int MB = M >> 7;
        GemmP gq = mkP(0, bnd);
        for (int z = 0; z < 3; z++) { gq.eB1[z] = eB1s[z]; gq.eB2[z] = eB2s[z]; gq.bB1[z] = bB1s[z]; }
        gq.C[0] = R_Q; gq.C[1] = R_K; gq.C[2] = R_V;
        gemm_mfma<<<dim3(6, MB, 3), 256, 0, stream>>>(gq, M, 768, 768, 0, 1.f / 4096.f, 0.f, 6);
        if (!userAttn) {
            attn_fused64<<<nseqTot * NHEAD, 256, 0, stream>>>(R_Q, R_K, R_V, mHis, cddA, gMid, s1h, s2h);
        } else {
            attn_flash400<<<8 * NHEAD * 25, 256, 0, stream>>>(R_Q, R_K, R_V, mHis, s1h, s2h);
        }
        GemmP go = mkP(3, bnd);
        go.C[0] = R_Q;
        gemm_mfma<<<dim3(6, MB, 1), 256, 0, stream>>>(go, M, 768, 768, 0, 1.f / 4096.f, 0.f, 6);
        add_ln2<<<M, 256, 0, stream>>>(R_X, R_Q, R_X, R_X, M, s1h, s2h, 1.f, nullptr, 0, 0, 64);
        GemmP g1 = mkP(4, bnd);
        g1.G1 = g1h; g1.G2 = g2h;
        gemm_mfma<<<dim3(24, MB, 1), 256, 0, stream>>>(g1, M, 3072, 768, 1, 1.f / 64.f, 16.f, 6);
        GemmP g2 = mkP(5, bnd);
        g2.A1 = g1h; g2.A2 = g2h; g2.C[0] = R_Q;
        gemm_mfma<<<dim3(6, MB, 1), 256, 0, stream>>>(g2, M, 768, 3072, 0, 1.f / 1024.f, 0.f, 2);
        add_ln2<<<M, 256, 0, stream>>>(R_X, R_Q, outA, outB, bnd, nullptr, nullptr, 0.f,
                                       clsArena, clsOffA, clsOffB, S);
    };

    // ---- history (+cdd in first chunk) encoder, NS his seqs per chunk ----
    int done = 0;
    bool first = true;
    while (done < 400) {
        int ns = NS < (400 - done) ? NS : (400 - done);
        int hisRows = ns * 64;
        int M = hisRows + (first ? 2560 : 0);
        int nseqTot = ns + (first ? 40 : 0);
        emb_pool2<<<nseqTot * 4, 256, 0, stream>>>(Pa, his_enc, cdd_enc, emb, R_X, s1h, s2h, done, ns);
        tf(M, hisRows, nseqTot, ns, hisA + (size_t)done * 64,
           hisH + (size_t)done * 64 * DIM, cddTrash, cls, done, 400, 64, false);
        done += ns;
        first = false;
    }

    // ---- candidate projection from cls rows 400..439 ----
    gemm_kernel<<<dim3(12, 1), 256, 0, stream>>>(cls + (size_t)400 * 768, pW, cddR, 40, 768, 768, 2, pb);

    // ---- user encoder + matching reducer (fp32, exact order) ----
    user_pool_kernel<<<8, 256, 0, stream>>>(cls, qU, user0);
    topk_kernel<<<400, 256, 0, stream>>>(hisH, user0, hisA, out + 40, kidI, psM);
    gather2<<<3200, 256, 0, stream>>>(hisH, kidI, R_X, s1h, s2h);

    // ---- user BERT over 3200 selected terms (all bert: bnd=0; flash400 attn) ----
    tf(3200, 0, 8, 0, psM, hisH, hisH, userC, 0, 0, 400, true);
    gemm_kernel<<<dim3(12, 1), 256, 0, stream>>>(userC, pW, userR, 8, 768, 768, 2, pb);

    final_kernel<<<8, 256, 0, stream>>>(cddR, userR, out);
}